// Round 1
// 345.962 us; speedup vs baseline: 1.2567x; 1.2567x over previous
//
#include <hip/hip_runtime.h>
#include <math.h>

// CirculantAttention on MI355X.
//   attn = softmax_n( N^{-3/2} * circ_corr(Xq, Xk) )   per (b,c) image
//   out  = (1/N)    *  circ_corr(attn, Xv)
// GEMMs in spatial domain via bf16x3-split MFMA. FFT: 8x16 two-phase
// in-register engine. Intermediates in bf16 (QK packed as one uint, V, oc);
// T (gate) stays fp32.
// R1: weights pre-split into fragment-ordered bf16 hi/lo planes by a tiny
// prep kernel (removes ~3300 VALU instrs/thread of redundant split work from
// gemm_qkvg); Q/K and V/T share one dual-accumulator core so B-fragment LDS
// reads are issued once per pair.

constexpr int CH    = 128;
constexpr int NSP   = 128 * 128;   // 16384
constexpr int BATCH = 8;
constexpr int NIMG  = BATCH * CH;  // 1024
constexpr int RS    = 130;         // fft complex row stride
constexpr int NT    = 1024;        // fft threads (16 waves)
constexpr int NW    = NT / 64;

// ======================= MFMA GEMM machinery =======================

typedef short short8 __attribute__((ext_vector_type(8)));
typedef float f32x4  __attribute__((ext_vector_type(4)));
union U8 { unsigned u[4]; short8 s; };

__device__ __forceinline__ unsigned bf16r(float x) {   // RNE -> low 16 bits
  unsigned u = __float_as_uint(x);
  return (u + 0x7FFFu + ((u >> 16) & 1u)) >> 16;
}
__device__ __forceinline__ float bflo(unsigned w) { return __uint_as_float(w << 16); }
__device__ __forceinline__ float bfhi(unsigned w) { return __uint_as_float(w & 0xFFFF0000u); }

__device__ __forceinline__ void split_pair(float e0, float e1,
                                           unsigned& hi, unsigned& lo) {
  const unsigned u0 = __float_as_uint(e0), u1 = __float_as_uint(e1);
  hi = (u0 >> 16) | (u1 & 0xFFFF0000u);
  const float r0 = e0 - __uint_as_float(u0 & 0xFFFF0000u);
  const float r1 = e1 - __uint_as_float(u1 & 0xFFFF0000u);
  lo = bf16r(r0) | (bf16r(r1) << 16);
}

__device__ __forceinline__ void load_a_frag(const float* wr, short8& ah, short8& al) {
  const float4 wa = *(const float4*)wr;
  const float4 wb = *(const float4*)(wr + 4);
  U8 hi, lo;
  split_pair(wa.x, wa.y, hi.u[0], lo.u[0]);
  split_pair(wa.z, wa.w, hi.u[1], lo.u[1]);
  split_pair(wb.x, wb.y, hi.u[2], lo.u[2]);
  split_pair(wb.z, wb.w, hi.u[3], lo.u[3]);
  ah = hi.s; al = lo.s;
}

// ---- weight pre-split: fragment-ordered bf16 hi/lo planes ----
// layout (short8 units): [(g*2+mbi)*2048 + (kg*4+mf)*128 + plane*64 + lane]
// g: 0=Q 1=K 2=V 3=gate 4=proj ; mbi = wave-row (wid>>1)

__global__ void prep_weights(const float* __restrict__ w_qkv,
                             const float* __restrict__ w_gate,
                             const float* __restrict__ w_proj,
                             short* __restrict__ wpre) {
  const int t = blockIdx.x * 256 + threadIdx.x;   // 10240 total
  const int lane = t & 63;
  const int mf   = (t >> 6) & 3;
  const int kg   = (t >> 8) & 3;
  const int mbi  = (t >> 10) & 1;
  const int g    = t >> 11;
  if (g >= 5) return;
  const float* W = (g < 3) ? (w_qkv + (size_t)g * CH * CH)
                           : (g == 3 ? w_gate : w_proj);
  const int row = mbi * 64 + mf * 16 + (lane & 15);
  const int k0  = kg * 32 + (lane >> 4) * 8;
  short8 ah, al;
  load_a_frag(W + (size_t)row * CH + k0, ah, al);
  const size_t base = ((size_t)(g * 2 + mbi) * 16 + kg * 4 + mf) * 1024;  // shorts
  *(short8*)(wpre + base + lane * 8)       = ah;
  *(short8*)(wpre + base + 512 + lane * 8) = al;
}

// xs: bf16 hi plane [0,8192), lo plane [8192,16384), XOR-swizzled words.

__device__ __forceinline__ void mfma_half(const short8* __restrict__ wf,
                                          const short8 bh[4], const short8 bl[4],
                                          f32x4 acc[4][4], int kg, int lane) {
  short8 ah[4], al[4];
#pragma unroll
  for (int mf = 0; mf < 4; ++mf) {
    const short8* p = wf + (kg * 4 + mf) * 128 + lane;
    ah[mf] = p[0];
    al[mf] = p[64];
  }
#pragma unroll
  for (int mf = 0; mf < 4; ++mf)
#pragma unroll
    for (int nf = 0; nf < 4; ++nf)
      acc[mf][nf] = __builtin_amdgcn_mfma_f32_16x16x32_bf16(al[mf], bh[nf], acc[mf][nf], 0, 0, 0);
#pragma unroll
  for (int mf = 0; mf < 4; ++mf)
#pragma unroll
    for (int nf = 0; nf < 4; ++nf)
      acc[mf][nf] = __builtin_amdgcn_mfma_f32_16x16x32_bf16(ah[mf], bl[nf], acc[mf][nf], 0, 0, 0);
#pragma unroll
  for (int mf = 0; mf < 4; ++mf)
#pragma unroll
    for (int nf = 0; nf < 4; ++nf)
      acc[mf][nf] = __builtin_amdgcn_mfma_f32_16x16x32_bf16(ah[mf], bh[nf], acc[mf][nf], 0, 0, 0);
}

// dual-GEMM core: B fragments read from LDS once, used for both weight sets
__device__ __forceinline__ void mfma_core2(const unsigned* xs,
                                           const short8* __restrict__ wfA,
                                           const short8* __restrict__ wfB,
                                           f32x4 aA[4][4], f32x4 aB[4][4], int tid) {
  const int lane = tid & 63, wid = tid >> 6;
  const int nb = (wid & 1) * 64;
  const int lm = lane & 15, quad = lane >> 4;
#pragma unroll
  for (int kg = 0; kg < 4; ++kg) {
    short8 bh[4], bl[4];
    const int kwb = (kg * 16 + quad * 4) ^ (lm << 2);
#pragma unroll
    for (int nf = 0; nf < 4; ++nf) {
      const unsigned* p = xs + (nb + nf * 16 + lm) * 64 + kwb;
      bh[nf] = *(const short8*)p;
      bl[nf] = *(const short8*)(p + 8192);
    }
    mfma_half(wfA, bh, bl, aA, kg, lane);
    mfma_half(wfB, bh, bl, aB, kg, lane);
  }
}

__device__ __forceinline__ void mfma_core1(const unsigned* xs,
                                           const short8* __restrict__ wf,
                                           f32x4 acc[4][4], int tid) {
  const int lane = tid & 63, wid = tid >> 6;
  const int nb = (wid & 1) * 64;
  const int lm = lane & 15, quad = lane >> 4;
#pragma unroll
  for (int kg = 0; kg < 4; ++kg) {
    short8 bh[4], bl[4];
    const int kwb = (kg * 16 + quad * 4) ^ (lm << 2);
#pragma unroll
    for (int nf = 0; nf < 4; ++nf) {
      const unsigned* p = xs + (nb + nf * 16 + lm) * 64 + kwb;
      bh[nf] = *(const short8*)p;
      bl[nf] = *(const short8*)(p + 8192);
    }
    mfma_half(wf, bh, bl, acc, kg, lane);
  }
}

// ---------------- GEMM 1: one block -> packed QK (bf16|bf16), V bf16, T fp32 ----------------

__global__ __launch_bounds__(256, 2)
void gemm_qkvg(const float* __restrict__ x, const short* __restrict__ wpre,
               const float* __restrict__ b_gate,
               unsigned* __restrict__ QKp, unsigned short* __restrict__ Vp,
               float* __restrict__ Tp) {
  __shared__ __align__(16) unsigned xs[16384];      // 64 KB
  __shared__ __align__(16) float bounce[4 * 528];   // 16x33 per wave
  const int tid = threadIdx.x;
  const int n0 = blockIdx.x * 128;
  const int b  = blockIdx.y;
  const float* xb = x + (size_t)b * CH * NSP;

  {
    const int tn = tid >> 3;
    const int tk = tid & 7;
#pragma unroll
    for (int i = 0; i < 8; ++i) {
      const int k = 2 * tk + 16 * i;
      const float* p0 = xb + (size_t)k * NSP + n0 + 4 * tn;
      const float4 a = *(const float4*)p0;
      const float4 c = *(const float4*)(p0 + NSP);
      const float a4[4] = {a.x, a.y, a.z, a.w};
      const float c4[4] = {c.x, c.y, c.z, c.w};
      const int kw = tk + 8 * i;
#pragma unroll
      for (int j = 0; j < 4; ++j) {
        const int nn = 4 * tn + j;
        unsigned hi, lo;
        split_pair(a4[j], c4[j], hi, lo);
        const int kws = kw ^ ((nn & 15) << 2);
        xs[nn * 64 + kws] = hi;
        xs[8192 + nn * 64 + kws] = lo;
      }
    }
  }
  __syncthreads();

  const int lane = tid & 63, wid = tid >> 6;
  const int mb = (wid >> 1) * 64, nb = (wid & 1) * 64;
  const int lm = lane & 15, quad = lane >> 4;
  const int mbi = wid >> 1;
  const short8* wp = (const short8*)wpre;
  const short8* wQ = wp + (size_t)(0 * 2 + mbi) * 2048;
  const short8* wK = wp + (size_t)(1 * 2 + mbi) * 2048;
  const short8* wV = wp + (size_t)(2 * 2 + mbi) * 2048;
  const short8* wG = wp + (size_t)(3 * 2 + mbi) * 2048;
  float* const bw = bounce + wid * 528;
  unsigned* const ubw = (unsigned*)bw;

  // Q and K accs live simultaneously (packed write); B frags read once
  f32x4 aq[4][4], ak[4][4];
#pragma unroll
  for (int mf = 0; mf < 4; ++mf)
#pragma unroll
    for (int nf = 0; nf < 4; ++nf) { aq[mf][nf] = (f32x4){0,0,0,0}; ak[mf][nf] = (f32x4){0,0,0,0}; }
  mfma_core2(xs, wQ, wK, aq, ak, tid);

#pragma unroll
  for (int mf = 0; mf < 4; ++mf) {
#pragma unroll
    for (int half = 0; half < 2; ++half) {
#pragma unroll
      for (int nn = 0; nn < 2; ++nn) {
        const int nf = half * 2 + nn;
#pragma unroll
        for (int i = 0; i < 4; ++i)
          ubw[(quad * 4 + i) * 33 + nn * 16 + lm] =
              bf16r(aq[mf][nf][i]) | (bf16r(ak[mf][nf][i]) << 16);
      }
#pragma unroll
      for (int j = 0; j < 2; ++j) {
        const int rl = (lane >> 3) + 8 * j;
        const int cl = (lane & 7) * 4;
        const uint4 v = *(const uint4*)(ubw + rl * 33 + cl);
        const int row = mb + mf * 16 + rl;
        *(uint4*)(QKp + ((size_t)b * CH + row) * NSP + n0 + nb + half * 32 + cl) = v;
      }
    }
  }

  // V (bf16) and T (silu, fp32); B frags read once
  f32x4 av[4][4], at[4][4];
#pragma unroll
  for (int mf = 0; mf < 4; ++mf)
#pragma unroll
    for (int nf = 0; nf < 4; ++nf) { av[mf][nf] = (f32x4){0,0,0,0}; at[mf][nf] = (f32x4){0,0,0,0}; }
  mfma_core2(xs, wV, wG, av, at, tid);

#pragma unroll
  for (int mf = 0; mf < 4; ++mf) {
#pragma unroll
    for (int half = 0; half < 2; ++half) {
#pragma unroll
      for (int nn = 0; nn < 2; ++nn) {
        const int nf = half * 2 + nn;
#pragma unroll
        for (int i = 0; i < 4; ++i)
          bw[(quad * 4 + i) * 33 + nn * 16 + lm] = av[mf][nf][i];
      }
#pragma unroll
      for (int j = 0; j < 2; ++j) {
        const int rl = (lane >> 3) + 8 * j;
        const int cl = (lane & 7) * 4;
        const float4 v = *(const float4*)(bw + rl * 33 + cl);
        const int row = mb + mf * 16 + rl;
        uint2 pv;
        pv.x = bf16r(v.x) | (bf16r(v.y) << 16);
        pv.y = bf16r(v.z) | (bf16r(v.w) << 16);
        *(uint2*)(Vp + ((size_t)b * CH + row) * NSP + n0 + nb + half * 32 + cl) = pv;
      }
    }
  }

#pragma unroll
  for (int mf = 0; mf < 4; ++mf) {
#pragma unroll
    for (int half = 0; half < 2; ++half) {
#pragma unroll
      for (int nn = 0; nn < 2; ++nn) {
        const int nf = half * 2 + nn;
#pragma unroll
        for (int i = 0; i < 4; ++i)
          bw[(quad * 4 + i) * 33 + nn * 16 + lm] = at[mf][nf][i];
      }
#pragma unroll
      for (int j = 0; j < 2; ++j) {
        const int rl = (lane >> 3) + 8 * j;
        const int cl = (lane & 7) * 4;
        float4 v = *(const float4*)(bw + rl * 33 + cl);
        const int row = mb + mf * 16 + rl;
        const float bg = b_gate[row];
        float e[4] = {v.x, v.y, v.z, v.w};
#pragma unroll
        for (int q = 0; q < 4; ++q) {
          const float g = e[q] + bg;
          e[q] = g / (1.0f + __expf(-g));
        }
        v = make_float4(e[0], e[1], e[2], e[3]);
        *(float4*)(Tp + ((size_t)b * CH + row) * NSP + n0 + nb + half * 32 + cl) = v;
      }
    }
  }
}

// ---------------- GEMM 2: w_proj @ (oc_bf16 .* t) + b_proj -> fp32 out ----------------

__device__ __forceinline__ void acc_to_bounce(float* bounce, f32x4 acc[4][4], int tid) {
  const int lane = tid & 63, wid = tid >> 6;
  const int mb = (wid >> 1) * 64;
  const int nb = (wid & 1) * 64;
  const int lm = lane & 15, quad = lane >> 4;
#pragma unroll
  for (int mf = 0; mf < 4; ++mf)
#pragma unroll
    for (int nf = 0; nf < 4; ++nf) {
      const int col = nb + nf * 16 + lm;
      const int r0 = mb + mf * 16 + quad * 4;
#pragma unroll
      for (int i = 0; i < 4; ++i)
        bounce[(r0 + i) * 132 + col] = acc[mf][nf][i];
    }
}

__global__ __launch_bounds__(256, 2)
void gemm_proj(const unsigned short* __restrict__ OC, const float* __restrict__ Tn,
               const short* __restrict__ wpre, const float* __restrict__ b_proj,
               float* __restrict__ outp) {
  __shared__ __align__(16) unsigned xs[16896];
  const int tid = threadIdx.x;
  const int n0 = blockIdx.x * 128;
  const int b = blockIdx.y;
  const unsigned short* ob = OC + (size_t)b * CH * NSP;
  const float* tb = Tn + (size_t)b * CH * NSP;

  {
    const int tn = tid >> 3;
    const int tk = tid & 7;
#pragma unroll
    for (int i = 0; i < 8; ++i) {
      const int k = 2 * tk + 16 * i;
      const uint2 ou0 = *(const uint2*)(ob + (size_t)k * NSP + n0 + 4 * tn);
      const uint2 ou1 = *(const uint2*)(ob + (size_t)(k + 1) * NSP + n0 + 4 * tn);
      const float* pt = tb + (size_t)k * NSP + n0 + 4 * tn;
      const float4 t0 = *(const float4*)pt;
      const float4 t1 = *(const float4*)(pt + NSP);
      const float z0[4] = {bflo(ou0.x) * t0.x, bfhi(ou0.x) * t0.y,
                           bflo(ou0.y) * t0.z, bfhi(ou0.y) * t0.w};
      const float z1[4] = {bflo(ou1.x) * t1.x, bfhi(ou1.x) * t1.y,
                           bflo(ou1.y) * t1.z, bfhi(ou1.y) * t1.w};
      const int kw = tk + 8 * i;
#pragma unroll
      for (int j = 0; j < 4; ++j) {
        const int nn = 4 * tn + j;
        unsigned hi, lo;
        split_pair(z0[j], z1[j], hi, lo);
        const int kws = kw ^ ((nn & 15) << 2);
        xs[nn * 64 + kws] = hi;
        xs[8192 + nn * 64 + kws] = lo;
      }
    }
  }
  __syncthreads();

  const int mbi = (tid >> 6) >> 1;
  const short8* wP = (const short8*)wpre + (size_t)(4 * 2 + mbi) * 2048;

  f32x4 acc[4][4];
#pragma unroll
  for (int mf = 0; mf < 4; ++mf)
#pragma unroll
    for (int nf = 0; nf < 4; ++nf) acc[mf][nf] = (f32x4){0,0,0,0};

  mfma_core1(xs, wP, acc, tid);

  __syncthreads();
  float* bounce = (float*)xs;
  acc_to_bounce(bounce, acc, tid);
  __syncthreads();

  const int rr = tid >> 5;
  const int c4i = (tid & 31) * 4;
#pragma unroll
  for (int i = 0; i < 16; ++i) {
    const int row = rr + 8 * i;
    const float bp = b_proj[row];
    float4 v = *(const float4*)(bounce + row * 132 + c4i);
    v.x += bp; v.y += bp; v.z += bp; v.w += bp;
    *(float4*)(outp + ((size_t)b * CH + row) * NSP + n0 + c4i) = v;
  }
}

// ======================= FFT attention =======================

__device__ __forceinline__ float2 cmul(float2 a, float2 b) {
  return make_float2(fmaf(a.x, b.x, -(a.y * b.y)), fmaf(a.x, b.y, a.y * b.x));
}
#define CADD(a,b) make_float2((a).x+(b).x,(a).y+(b).y)
#define CSUB(a,b) make_float2((a).x-(b).x,(a).y-(b).y)
#define MULNI(t)  make_float2((t).y, -(t).x)
constexpr float C45 = 0.7071067811865476f;

__device__ __forceinline__ void fft8(float2* x) {
  float2 t;
  t = CSUB(x[0],x[4]); x[0]=CADD(x[0],x[4]); x[4]=t;
  t = CSUB(x[1],x[5]); x[1]=CADD(x[1],x[5]); x[5]=make_float2(C45*(t.x+t.y), C45*(t.y-t.x));
  t = CSUB(x[2],x[6]); x[2]=CADD(x[2],x[6]); x[6]=MULNI(t);
  t = CSUB(x[3],x[7]); x[3]=CADD(x[3],x[7]); x[7]=make_float2(C45*(t.y-t.x), -C45*(t.x+t.y));
  t = CSUB(x[0],x[2]); x[0]=CADD(x[0],x[2]); x[2]=t;
  t = CSUB(x[1],x[3]); x[1]=CADD(x[1],x[3]); x[3]=MULNI(t);
  t = CSUB(x[4],x[6]); x[4]=CADD(x[4],x[6]); x[6]=t;
  t = CSUB(x[5],x[7]); x[5]=CADD(x[5],x[7]); x[7]=MULNI(t);
  t = CSUB(x[0],x[1]); x[0]=CADD(x[0],x[1]); x[1]=t;
  t = CSUB(x[2],x[3]); x[2]=CADD(x[2],x[3]); x[3]=t;
  t = CSUB(x[4],x[5]); x[4]=CADD(x[4],x[5]); x[5]=t;
  t = CSUB(x[6],x[7]); x[6]=CADD(x[6],x[7]); x[7]=t;
}

__device__ __forceinline__ void fft16(float2* z) {
  float2 t;
  t=CSUB(z[0],z[8]);   z[0]=CADD(z[0],z[8]);   z[8]=t;
  t=CSUB(z[1],z[9]);   z[1]=CADD(z[1],z[9]);   z[9]=cmul(t,  make_float2( 0.9238795325f,-0.3826834324f));
  t=CSUB(z[2],z[10]);  z[2]=CADD(z[2],z[10]);  z[10]=make_float2(C45*(t.x+t.y), C45*(t.y-t.x));
  t=CSUB(z[3],z[11]);  z[3]=CADD(z[3],z[11]);  z[11]=cmul(t, make_float2( 0.3826834324f,-0.9238795325f));
  t=CSUB(z[4],z[12]);  z[4]=CADD(z[4],z[12]);  z[12]=MULNI(t);
  t=CSUB(z[5],z[13]);  z[5]=CADD(z[5],z[13]);  z[13]=cmul(t, make_float2(-0.3826834324f,-0.9238795325f));
  t=CSUB(z[6],z[14]);  z[6]=CADD(z[6],z[14]);  z[14]=make_float2(C45*(t.y-t.x), -C45*(t.x+t.y));
  t=CSUB(z[7],z[15]);  z[7]=CADD(z[7],z[15]);  z[15]=cmul(t, make_float2(-0.9238795325f,-0.3826834324f));
  t=CSUB(z[0],z[4]);   z[0]=CADD(z[0],z[4]);   z[4]=t;
  t=CSUB(z[1],z[5]);   z[1]=CADD(z[1],z[5]);   z[5]=make_float2(C45*(t.x+t.y), C45*(t.y-t.x));
  t=CSUB(z[2],z[6]);   z[2]=CADD(z[2],z[6]);   z[6]=MULNI(t);
  t=CSUB(z[3],z[7]);   z[3]=CADD(z[3],z[7]);   z[7]=make_float2(C45*(t.y-t.x), -C45*(t.x+t.y));
  t=CSUB(z[8],z[12]);  z[8]=CADD(z[8],z[12]);  z[12]=t;
  t=CSUB(z[9],z[13]);  z[9]=CADD(z[9],z[13]);  z[13]=make_float2(C45*(t.x+t.y), C45*(t.y-t.x));
  t=CSUB(z[10],z[14]); z[10]=CADD(z[10],z[14]); z[14]=MULNI(t);
  t=CSUB(z[11],z[15]); z[11]=CADD(z[11],z[15]); z[15]=make_float2(C45*(t.y-t.x), -C45*(t.x+t.y));
  t=CSUB(z[0],z[2]);   z[0]=CADD(z[0],z[2]);   z[2]=t;
  t=CSUB(z[1],z[3]);   z[1]=CADD(z[1],z[3]);   z[3]=MULNI(t);
  t=CSUB(z[4],z[6]);   z[4]=CADD(z[4],z[6]);   z[6]=t;
  t=CSUB(z[5],z[7]);   z[5]=CADD(z[5],z[7]);   z[7]=MULNI(t);
  t=CSUB(z[8],z[10]);  z[8]=CADD(z[8],z[10]);  z[10]=t;
  t=CSUB(z[9],z[11]);  z[9]=CADD(z[9],z[11]);  z[11]=MULNI(t);
  t=CSUB(z[12],z[14]); z[12]=CADD(z[12],z[14]); z[14]=t;
  t=CSUB(z[13],z[15]); z[13]=CADD(z[13],z[15]); z[15]=MULNI(t);
  t=CSUB(z[0],z[1]);   z[0]=CADD(z[0],z[1]);   z[1]=t;
  t=CSUB(z[2],z[3]);   z[2]=CADD(z[2],z[3]);   z[3]=t;
  t=CSUB(z[4],z[5]);   z[4]=CADD(z[4],z[5]);   z[5]=t;
  t=CSUB(z[6],z[7]);   z[6]=CADD(z[6],z[7]);   z[7]=t;
  t=CSUB(z[8],z[9]);   z[8]=CADD(z[8],z[9]);   z[9]=t;
  t=CSUB(z[10],z[11]); z[10]=CADD(z[10],z[11]); z[11]=t;
  t=CSUB(z[12],z[13]); z[12]=CADD(z[12],z[13]); z[13]=t;
  t=CSUB(z[14],z[15]); z[14]=CADD(z[14],z[15]); z[15]=t;
}

// SRC: 0 = LDS complex, 1 = global packed QK (z = Q + iK), 2 = LDS .x + global V bf16
// EPI: 1 = apply exp(x*escale) to .x on final write, accumulate lane-sum
template<int SPT, int SLN, int SRC, int EPI>
__device__ __forceinline__ void fft_pass(float2* img, const float2* tw,
                                         int lane, int wid,
                                         const unsigned* gqk,
                                         const unsigned short* gv,
                                         float escale, float& lsum) {
  const int n2 = lane & 15, rr = lane >> 4;
  constexpr int br3[8] = {0,4,2,6,1,5,3,7};
#pragma unroll
  for (int u = 0; u < 2; ++u) {
    const int line = wid * 8 + u * 4 + rr;
    const int lb = SLN * line;
    float2 x[8];
    if constexpr (SRC == 0) {
#pragma unroll
      for (int n1 = 0; n1 < 8; ++n1) x[n1] = img[lb + SPT * (16 * n1 + n2)];
    } else if constexpr (SRC == 1) {
#pragma unroll
      for (int n1 = 0; n1 < 8; ++n1) {
        const unsigned qk = gqk[line * 128 + 16 * n1 + n2];
        x[n1] = make_float2(bflo(qk), bfhi(qk));
      }
    } else {
#pragma unroll
      for (int n1 = 0; n1 < 8; ++n1) {
        const float a = img[lb + SPT * (16 * n1 + n2)].x;
        const unsigned short vv = gv[line * 128 + 16 * n1 + n2];
        x[n1] = make_float2(a, __uint_as_float((unsigned)vv << 16));
      }
    }
    fft8(x);
#pragma unroll
    for (int m = 0; m < 8; ++m) {
      const int k1 = br3[m];
      const float2 y = (k1 == 0) ? x[m] : cmul(x[m], tw[k1 - 1]);
      img[lb + SPT * (16 * k1 + (n2 ^ k1))] = y;
    }
  }
  const int k1 = lane & 7;
  const int lb = SLN * (wid * 8 + (lane >> 3));
  const int kb = 16 * k1;
  float2 z[16];
#pragma unroll
  for (int j = 0; j < 16; ++j) z[j] = img[lb + SPT * (kb + (j ^ k1))];
  fft16(z);
  constexpr int br4[16] = {0,8,4,12,2,10,6,14,1,9,5,13,3,11,7,15};
#pragma unroll
  for (int m = 0; m < 16; ++m) {
    const int a = lb + SPT * (k1 + 8 * br4[m]);
    if constexpr (EPI == 1) {
      const float ex = __expf(z[m].x * escale);
      lsum += ex;
      img[a] = make_float2(ex, 0.0f);
    } else {
      img[a] = z[m];
    }
  }
}

// Exact-pair cross-spectrum: Y = conj(A_f)*B_f from the packed spectrum,
// stored conj(Y) so a second forward FFT == unnormalized inverse.
__device__ __forceinline__ void cross_spectrum(float2* img, int tid) {
#pragma unroll
  for (int i = 0; i < 8; ++i) {
    const int pid = tid + (i << 10);
    int fr, fc;
    if (pid < 8064)      { fc = 1 + (pid >> 7); fr = pid & 127; }
    else if (pid < 8127) { fc = 0;  fr = pid - 8063; }
    else if (pid < 8190) { fc = 64; fr = pid - 8126; }
    else if (pid == 8190) {
#pragma unroll
      for (int s = 0; s < 4; ++s) {
        const int a = ((s >> 1) * 64) * RS + (s & 1) * 64;
        const float2 zz = img[a];
        img[a] = make_float2(zz.x * zz.y, 0.0f);
      }
      continue;
    } else continue;
    const int gr = (128 - fr) & 127, gc = 128 - fc >= 128 ? 0 : (128 - fc) & 127;
    const int f = fr * RS + fc, g = gr * RS + gc;
    const float2 zf = img[f], zg = img[g];
    const float qr = 0.5f * (zf.x + zg.x), qi = 0.5f * (zf.y - zg.y);
    const float kr = 0.5f * (zf.y + zg.y), ki = 0.5f * (zg.x - zf.x);
    const float yr = qr * kr + qi * ki;
    const float yi = qr * ki - qi * kr;
    img[f] = make_float2(yr, -yi);
    img[g] = make_float2(yr, yi);
  }
}

__global__ __launch_bounds__(NT)
void fft_attn_fused(const unsigned* __restrict__ QKin,
                    const unsigned short* __restrict__ Vin,
                    unsigned short* __restrict__ Out) {
  __shared__ float2 img[128 * RS];
  __shared__ float red[NW];
  const int tid = threadIdx.x, lane = tid & 63, wid = tid >> 6;
  const size_t off = (size_t)blockIdx.x * NSP;
  const unsigned* gqk = QKin + off;
  const unsigned short* gv = Vin + off;

  float2 tw[7];
  {
    const int n2 = lane & 15;
#pragma unroll
    for (int k = 1; k < 8; ++k) {
      float s, c;
      sincosf(6.283185307179586f * (float)(n2 * k) * (1.0f / 128.0f), &s, &c);
      tw[k - 1] = make_float2(c, -s);
    }
  }
  float dummy = 0.0f;

  // ---- stage 1: forward FFT of z = Q + iK (rows read straight from global) ----
  fft_pass<1, RS, 1, 0>(img, tw, lane, wid, gqk, nullptr, 0.0f, dummy);
  __syncthreads();
  fft_pass<RS, 1, 0, 0>(img, tw, lane, wid, nullptr, nullptr, 0.0f, dummy);
  __syncthreads();
  cross_spectrum(img, tid);
  __syncthreads();
  // inverse (conj trick) with fused exp on the final col pass
  const float escale = 1.0f / 2097152.0f;   // N^{-3/2}; |logit| O(1) -> no max-sub
  float lsum = 0.0f;
  fft_pass<1, RS, 0, 0>(img, tw, lane, wid, nullptr, nullptr, 0.0f, dummy);
  __syncthreads();
  fft_pass<RS, 1, 0, 1>(img, tw, lane, wid, nullptr, nullptr, escale, lsum);
  __syncthreads();

  // block-reduce sum of exp; normalization folds into final output scale
#pragma unroll
  for (int s = 32; s >= 1; s >>= 1) lsum += __shfl_xor(lsum, s, 64);
  if (lane == 0) red[wid] = lsum;
  __syncthreads();
  float tot = 0.0f;
#pragma unroll
  for (int w = 0; w < NW; ++w) tot += red[w];
  const float inv = 1.0f / tot;

  // ---- stage 2: forward FFT of z = exp(logit) + iV (V read from global in-pass) ----
  fft_pass<1, RS, 2, 0>(img, tw, lane, wid, nullptr, gv, 0.0f, dummy);
  __syncthreads();
  fft_pass<RS, 1, 0, 0>(img, tw, lane, wid, nullptr, nullptr, 0.0f, dummy);
  __syncthreads();
  cross_spectrum(img, tid);
  __syncthreads();
  fft_pass<1, RS, 0, 0>(img, tw, lane, wid, nullptr, nullptr, 0.0f, dummy);
  __syncthreads();
  fft_pass<RS, 1, 0, 0>(img, tw, lane, wid, nullptr, nullptr, 0.0f, dummy);
  __syncthreads();

  const float os = inv * (1.0f / 16384.0f);   // softmax 1/sum * 1/N
#pragma unroll
  for (int i = 0; i < 4; ++i) {
    const int e = (tid + i * NT) * 4;
    const float2* base = img + (e >> 7) * RS + (e & 127);
    const float4 a = *(const float4*)base;        // re0, im0, re1, im1
    const float4 c = *(const float4*)(base + 2);  // re2, im2, re3, im3
    uint2 o;
    o.x = bf16r(a.x * os) | (bf16r(a.z * os) << 16);
    o.y = bf16r(c.x * os) | (bf16r(c.z * os) << 16);
    *(uint2*)(Out + off + e) = o;
  }
}

// ---------------- launch ----------------

extern "C" void kernel_launch(void* const* d_in, const int* in_sizes, int n_in,
                              void* d_out, int out_size, void* d_ws, size_t ws_size,
                              hipStream_t stream) {
  const float* x      = (const float*)d_in[0];
  const float* w_qkv  = (const float*)d_in[1];
  const float* w_gate = (const float*)d_in[2];
  const float* b_gate = (const float*)d_in[3];
  const float* w_proj = (const float*)d_in[4];
  const float* b_proj = (const float*)d_in[5];
  float* outp = (float*)d_out;

  const size_t SZ = (size_t)BATCH * CH * NSP;   // 16,777,216 elements
  char* base = (char*)d_ws;
  unsigned*       QK = (unsigned*)base;                    // 64 MiB
  unsigned short* V  = (unsigned short*)(base + SZ * 4);   // 32 MiB
  float*          T  = (float*)(base + SZ * 6);            // 64 MiB
  unsigned short* OC = (unsigned short*)(base + SZ * 10);  // 32 MiB
  short*          WP = (short*)(base + SZ * 12);           // 320 KiB pre-split weights

  prep_weights<<<40, 256, 0, stream>>>(w_qkv, w_gate, w_proj, WP);

  dim3 g1(128, BATCH);
  gemm_qkvg<<<g1, 256, 0, stream>>>(x, WP, b_gate, QK, V, T);

  fft_attn_fused<<<NIMG, NT, 0, stream>>>(QK, V, OC);

  dim3 g2(128, BATCH);
  gemm_proj<<<g2, 256, 0, stream>>>(OC, T, WP, b_proj, outp);
}